// Round 3
// baseline (170.566 us; speedup 1.0000x reference)
//
#include <hip/hip_runtime.h>

// Fused: offset = conv3x3(x,w1)+b1 ; out = deform_conv(x, offset, w2)+b2
// x: (8,3,384,384) f32 ; out: (8,3,382,382) f32
// R3 = R1 (1 px/thread, VGPR~60, 8 waves/SIMD) + R2's verified wins:
//  - batch-per-XCD swizzle (b = blockIdx.x & 7): FETCH 39->7 MB measured.
//  - non-temporal output stores.
// R2 lesson: 2 px/thread pushed VGPR 60->116, halving occupancy (38->19%) --
// net regression in this latency-bound kernel. TLP > ILP here.

#define BB 8
#define CC 3
#define HH 384
#define WW 384
#define HO 382
#define WO 382
#define HW (HH * WW)
#define PIX_PER_BATCH (HO * WO)                              // 145924
#define BLOCKS_PER_BATCH ((PIX_PER_BATCH + 255) / 256)       // 571

__global__ __launch_bounds__(256, 8) void deform_fused_kernel(
    const float* __restrict__ x,
    const float* __restrict__ w1,
    const float* __restrict__ b1,
    const float* __restrict__ w2,
    const float* __restrict__ b2,
    float* __restrict__ out)
{
    __shared__ float s_w1[486];   // (18,27)
    __shared__ float s_b1[18];
    __shared__ float s_w2[81];    // (3,3,9) : o,c,k
    __shared__ float s_b2[3];

    for (int i = threadIdx.x; i < 486; i += 256) s_w1[i] = w1[i];
    for (int i = threadIdx.x; i < 81;  i += 256) s_w2[i] = w2[i];
    if (threadIdx.x < 18) s_b1[threadIdx.x] = b1[threadIdx.x];
    if (threadIdx.x < 3)  s_b2[threadIdx.x] = b2[threadIdx.x];
    __syncthreads();

    const int b    = blockIdx.x & 7;          // XCD-locality: batch per XCD
    const int tile = blockIdx.x >> 3;
    const int idx  = tile * 256 + threadIdx.x;
    if (idx >= PIX_PER_BATCH) return;

    const int wo = idx % WO;
    const int ho = idx / WO;

    const float* xb = x + (long)b * CC * HW;

    // 3x3x3 input neighborhood (reused by the offset conv)
    float xv[3][3][3];
#pragma unroll
    for (int c = 0; c < 3; ++c)
#pragma unroll
        for (int i = 0; i < 3; ++i)
#pragma unroll
            for (int j = 0; j < 3; ++j)
                xv[c][i][j] = xb[c * HW + (ho + i) * WW + (wo + j)];

    // 18 offset channels: off[2k]=dy_k, off[2k+1]=dx_k
    float off[18];
#pragma unroll
    for (int oc = 0; oc < 18; ++oc) {
        float a = s_b1[oc];
        const float* wp = s_w1 + oc * 27;
#pragma unroll
        for (int c = 0; c < 3; ++c)
#pragma unroll
            for (int i = 0; i < 3; ++i)
#pragma unroll
                for (int j = 0; j < 3; ++j)
                    a = fmaf(xv[c][i][j], wp[c * 9 + i * 3 + j], a);
        off[oc] = a;
    }

    float acc0 = s_b2[0], acc1 = s_b2[1], acc2 = s_b2[2];

    const float* xc0 = xb;
    const float* xc1 = xb + HW;
    const float* xc2 = xb + 2 * HW;

#pragma unroll
    for (int k = 0; k < 9; ++k) {
        const int kh = k / 3, kw = k % 3;
        const float py = (float)(ho + kh) + off[2 * k];
        const float px = (float)(wo + kw) + off[2 * k + 1];
        const float y0f = floorf(py);
        const float x0f = floorf(px);
        const float wy = py - y0f;
        const float wx = px - x0f;
        const int y0 = (int)y0f;
        const int x0 = (int)x0f;

        const float w00 = (1.f - wy) * (1.f - wx);
        const float w01 = (1.f - wy) * wx;
        const float w10 = wy * (1.f - wx);
        const float w11 = wy * wx;

        float v0 = 0.f, v1 = 0.f, v2 = 0.f;

#pragma unroll
        for (int corner = 0; corner < 4; ++corner) {
            const int yc = y0 + (corner >> 1);
            const int xc = x0 + (corner & 1);
            const float wt = (corner == 0) ? w00 : (corner == 1) ? w01
                           : (corner == 2) ? w10 : w11;
            const bool valid = (yc >= 0) & (yc <= HH - 1) & (xc >= 0) & (xc <= WW - 1);
            const int yi = min(max(yc, 0), HH - 1);
            const int xi = min(max(xc, 0), WW - 1);
            const float wv = valid ? wt : 0.f;
            const int base = yi * WW + xi;
            v0 = fmaf(wv, xc0[base], v0);
            v1 = fmaf(wv, xc1[base], v1);
            v2 = fmaf(wv, xc2[base], v2);
        }

        acc0 = fmaf(s_w2[0 * 27 + 0 * 9 + k], v0, acc0);
        acc0 = fmaf(s_w2[0 * 27 + 1 * 9 + k], v1, acc0);
        acc0 = fmaf(s_w2[0 * 27 + 2 * 9 + k], v2, acc0);
        acc1 = fmaf(s_w2[1 * 27 + 0 * 9 + k], v0, acc1);
        acc1 = fmaf(s_w2[1 * 27 + 1 * 9 + k], v1, acc1);
        acc1 = fmaf(s_w2[1 * 27 + 2 * 9 + k], v2, acc1);
        acc2 = fmaf(s_w2[2 * 27 + 0 * 9 + k], v0, acc2);
        acc2 = fmaf(s_w2[2 * 27 + 1 * 9 + k], v1, acc2);
        acc2 = fmaf(s_w2[2 * 27 + 2 * 9 + k], v2, acc2);
    }

    const long obase = ((long)(b * 3) * HO + ho) * WO + wo;
    __builtin_nontemporal_store(acc0, out + obase);
    __builtin_nontemporal_store(acc1, out + obase + (long)HO * WO);
    __builtin_nontemporal_store(acc2, out + obase + 2L * HO * WO);
}

extern "C" void kernel_launch(void* const* d_in, const int* in_sizes, int n_in,
                              void* d_out, int out_size, void* d_ws, size_t ws_size,
                              hipStream_t stream) {
    const float* x  = (const float*)d_in[0];
    const float* w1 = (const float*)d_in[1];
    const float* b1 = (const float*)d_in[2];
    const float* w2 = (const float*)d_in[3];
    const float* b2 = (const float*)d_in[4];
    float* out = (float*)d_out;

    const int blocks = BLOCKS_PER_BATCH * BB;   // 571*8 = 4568
    deform_fused_kernel<<<blocks, 256, 0, stream>>>(x, w1, b1, w2, b2, out);
}

// Round 4
// 150.999 us; speedup vs baseline: 1.1296x; 1.1296x over previous
//
#include <hip/hip_runtime.h>

// Fused: offset = conv3x3(x,w1)+b1 ; out = deform_conv(x, offset, w2)+b2
// x: (8,3,384,384) f32 ; out: (8,3,382,382) f32
// R4 = R1 codegen (1 px/thread, plain launch_bounds(256) -> VGPR~60, no spill)
//      + R2's verified wins: XCD batch swizzle (FETCH 39->7 MB), NT stores.
// R3 lesson: __launch_bounds__(256,8) capped VGPR at 32 -> spills -> 110MB of
// scratch HBM traffic (WRITE 14->89MB). Never cap below ~60 VGPR for this body.

#define BB 8
#define CC 3
#define HH 384
#define WW 384
#define HO 382
#define WO 382
#define HW (HH * WW)
#define PIX_PER_BATCH (HO * WO)                              // 145924
#define BLOCKS_PER_BATCH ((PIX_PER_BATCH + 255) / 256)       // 571

__global__ __launch_bounds__(256) void deform_fused_kernel(
    const float* __restrict__ x,
    const float* __restrict__ w1,
    const float* __restrict__ b1,
    const float* __restrict__ w2,
    const float* __restrict__ b2,
    float* __restrict__ out)
{
    __shared__ float s_w1[486];   // (18,27)
    __shared__ float s_b1[18];
    __shared__ float s_w2[81];    // (3,3,9) : o,c,k
    __shared__ float s_b2[3];

    for (int i = threadIdx.x; i < 486; i += 256) s_w1[i] = w1[i];
    for (int i = threadIdx.x; i < 81;  i += 256) s_w2[i] = w2[i];
    if (threadIdx.x < 18) s_b1[threadIdx.x] = b1[threadIdx.x];
    if (threadIdx.x < 3)  s_b2[threadIdx.x] = b2[threadIdx.x];
    __syncthreads();

    const int b    = blockIdx.x & 7;          // XCD-locality: batch per XCD
    const int tile = blockIdx.x >> 3;
    const int idx  = tile * 256 + threadIdx.x;
    if (idx >= PIX_PER_BATCH) return;

    const int wo = idx % WO;
    const int ho = idx / WO;

    const float* xb = x + (long)b * CC * HW;

    // 3x3x3 input neighborhood (reused by the offset conv)
    float xv[3][3][3];
#pragma unroll
    for (int c = 0; c < 3; ++c)
#pragma unroll
        for (int i = 0; i < 3; ++i)
#pragma unroll
            for (int j = 0; j < 3; ++j)
                xv[c][i][j] = xb[c * HW + (ho + i) * WW + (wo + j)];

    // 18 offset channels: off[2k]=dy_k, off[2k+1]=dx_k
    float off[18];
#pragma unroll
    for (int oc = 0; oc < 18; ++oc) {
        float a = s_b1[oc];
        const float* wp = s_w1 + oc * 27;
#pragma unroll
        for (int c = 0; c < 3; ++c)
#pragma unroll
            for (int i = 0; i < 3; ++i)
#pragma unroll
                for (int j = 0; j < 3; ++j)
                    a = fmaf(xv[c][i][j], wp[c * 9 + i * 3 + j], a);
        off[oc] = a;
    }

    float acc0 = s_b2[0], acc1 = s_b2[1], acc2 = s_b2[2];

    const float* xc0 = xb;
    const float* xc1 = xb + HW;
    const float* xc2 = xb + 2 * HW;

#pragma unroll
    for (int k = 0; k < 9; ++k) {
        const int kh = k / 3, kw = k % 3;
        const float py = (float)(ho + kh) + off[2 * k];
        const float px = (float)(wo + kw) + off[2 * k + 1];
        const float y0f = floorf(py);
        const float x0f = floorf(px);
        const float wy = py - y0f;
        const float wx = px - x0f;
        const int y0 = (int)y0f;
        const int x0 = (int)x0f;

        const float w00 = (1.f - wy) * (1.f - wx);
        const float w01 = (1.f - wy) * wx;
        const float w10 = wy * (1.f - wx);
        const float w11 = wy * wx;

        float v0 = 0.f, v1 = 0.f, v2 = 0.f;

#pragma unroll
        for (int corner = 0; corner < 4; ++corner) {
            const int yc = y0 + (corner >> 1);
            const int xc = x0 + (corner & 1);
            const float wt = (corner == 0) ? w00 : (corner == 1) ? w01
                           : (corner == 2) ? w10 : w11;
            const bool valid = (yc >= 0) & (yc <= HH - 1) & (xc >= 0) & (xc <= WW - 1);
            const int yi = min(max(yc, 0), HH - 1);
            const int xi = min(max(xc, 0), WW - 1);
            const float wv = valid ? wt : 0.f;
            const int base = yi * WW + xi;
            v0 = fmaf(wv, xc0[base], v0);
            v1 = fmaf(wv, xc1[base], v1);
            v2 = fmaf(wv, xc2[base], v2);
        }

        acc0 = fmaf(s_w2[0 * 27 + 0 * 9 + k], v0, acc0);
        acc0 = fmaf(s_w2[0 * 27 + 1 * 9 + k], v1, acc0);
        acc0 = fmaf(s_w2[0 * 27 + 2 * 9 + k], v2, acc0);
        acc1 = fmaf(s_w2[1 * 27 + 0 * 9 + k], v0, acc1);
        acc1 = fmaf(s_w2[1 * 27 + 1 * 9 + k], v1, acc1);
        acc1 = fmaf(s_w2[1 * 27 + 2 * 9 + k], v2, acc1);
        acc2 = fmaf(s_w2[2 * 27 + 0 * 9 + k], v0, acc2);
        acc2 = fmaf(s_w2[2 * 27 + 1 * 9 + k], v1, acc2);
        acc2 = fmaf(s_w2[2 * 27 + 2 * 9 + k], v2, acc2);
    }

    const long obase = ((long)(b * 3) * HO + ho) * WO + wo;
    __builtin_nontemporal_store(acc0, out + obase);
    __builtin_nontemporal_store(acc1, out + obase + (long)HO * WO);
    __builtin_nontemporal_store(acc2, out + obase + 2L * HO * WO);
}

extern "C" void kernel_launch(void* const* d_in, const int* in_sizes, int n_in,
                              void* d_out, int out_size, void* d_ws, size_t ws_size,
                              hipStream_t stream) {
    const float* x  = (const float*)d_in[0];
    const float* w1 = (const float*)d_in[1];
    const float* b1 = (const float*)d_in[2];
    const float* w2 = (const float*)d_in[3];
    const float* b2 = (const float*)d_in[4];
    float* out = (float*)d_out;

    const int blocks = BLOCKS_PER_BATCH * BB;   // 571*8 = 4568
    deform_fused_kernel<<<blocks, 256, 0, stream>>>(x, w1, b1, w2, b2, out);
}

// Round 5
// 143.952 us; speedup vs baseline: 1.1849x; 1.0490x over previous
//
#include <hip/hip_runtime.h>

// Fused: offset = conv3x3(x,w1)+b1 ; out = deform_conv(x, offset, w2)+b2
// x: (8,3,384,384) f32 ; out: (8,3,382,382) f32
// R5: pair-gather restructure. Per bilinear tap the 4 corners are 2 rows x 2
// adjacent cols -> 6 dwordx2 gathers (3ch x 2rows) at xbase=clamp(x0,0,382),
// corners resolved by branchless selects (exactly replicates reference's
// clip-index + zero-weight-on-invalid semantics). Gathers 36->18/thread,
// neighborhood loads 27->18, clamp/validity VALU ~-40%/tap.
// Kept from R2/R4 (verified): XCD batch swizzle (FETCH 39->7MB), NT stores,
// plain launch_bounds(256) (R3: capping to 8 waves/EU forced VGPR=32 -> 110MB
// of scratch spill traffic).

#define BB 8
#define CC 3
#define HH 384
#define WW 384
#define HO 382
#define WO 382
#define HW (HH * WW)
#define PIX_PER_BATCH (HO * WO)                              // 145924
#define BLOCKS_PER_BATCH ((PIX_PER_BATCH + 255) / 256)       // 571

typedef float v2f __attribute__((ext_vector_type(2), aligned(4)));

__global__ __launch_bounds__(256) void deform_fused_kernel(
    const float* __restrict__ x,
    const float* __restrict__ w1,
    const float* __restrict__ b1,
    const float* __restrict__ w2,
    const float* __restrict__ b2,
    float* __restrict__ out)
{
    __shared__ float s_w1[486];   // (18,27)
    __shared__ float s_b1[18];
    __shared__ float s_w2[81];    // (3,3,9) : o,c,k
    __shared__ float s_b2[3];

    for (int i = threadIdx.x; i < 486; i += 256) s_w1[i] = w1[i];
    for (int i = threadIdx.x; i < 81;  i += 256) s_w2[i] = w2[i];
    if (threadIdx.x < 18) s_b1[threadIdx.x] = b1[threadIdx.x];
    if (threadIdx.x < 3)  s_b2[threadIdx.x] = b2[threadIdx.x];
    __syncthreads();

    const int b    = blockIdx.x & 7;          // XCD-locality: batch per XCD
    const int tile = blockIdx.x >> 3;
    const int idx  = tile * 256 + threadIdx.x;
    if (idx >= PIX_PER_BATCH) return;

    const int wo = idx % WO;
    const int ho = idx / WO;

    const float* xb = x + (long)b * CC * HW;

    // 3ch x 3rows x 3cols neighborhood: v2f + scalar per row (18 loads)
    float xv[3][3][3];
#pragma unroll
    for (int c = 0; c < 3; ++c)
#pragma unroll
        for (int i = 0; i < 3; ++i) {
            const float* rp = xb + c * HW + (ho + i) * WW + wo;
            const v2f p = *(const v2f*)rp;
            xv[c][i][0] = p.x;
            xv[c][i][1] = p.y;
            xv[c][i][2] = rp[2];
        }

    // 18 offset channels: off[2k]=dy_k, off[2k+1]=dx_k
    float off[18];
#pragma unroll
    for (int oc = 0; oc < 18; ++oc) {
        float a = s_b1[oc];
        const float* wp = s_w1 + oc * 27;
#pragma unroll
        for (int c = 0; c < 3; ++c)
#pragma unroll
            for (int i = 0; i < 3; ++i)
#pragma unroll
                for (int j = 0; j < 3; ++j)
                    a = fmaf(xv[c][i][j], wp[c * 9 + i * 3 + j], a);
        off[oc] = a;
    }

    float acc0 = s_b2[0], acc1 = s_b2[1], acc2 = s_b2[2];

    const float* xc0 = xb;
    const float* xc1 = xb + HW;
    const float* xc2 = xb + 2 * HW;

#pragma unroll
    for (int k = 0; k < 9; ++k) {
        const int kh = k / 3, kw = k % 3;
        const float py = (float)(ho + kh) + off[2 * k];
        const float px = (float)(wo + kw) + off[2 * k + 1];
        const float y0f = floorf(py);
        const float x0f = floorf(px);
        const float wy = py - y0f;
        const float wx = px - x0f;
        const int y0 = (int)y0f;
        const int x0 = (int)x0f;

        // row indices (clamped) + x pair base
        const int ry0 = min(max(y0, 0), HH - 1);
        const int ry1 = min(max(y0 + 1, 0), HH - 1);
        const int xbs = min(max(x0, 0), WW - 2);

        // validity folded into weights (matches ref: wgt * valid)
        const bool vy0 = (y0 >= 0) & (y0 <= HH - 1);
        const bool vy1 = (y0 >= -1) & (y0 <= HH - 2);
        const bool vx0 = (x0 >= 0) & (x0 <= WW - 1);
        const bool vx1 = (x0 >= -1) & (x0 <= WW - 2);
        const float wy0m = vy0 ? (1.f - wy) : 0.f;
        const float wy1m = vy1 ? wy : 0.f;
        const float wx0m = vx0 ? (1.f - wx) : 0.f;
        const float wx1m = vx1 ? wx : 0.f;
        const float w00 = wy0m * wx0m;
        const float w01 = wy0m * wx1m;
        const float w10 = wy1m * wx0m;
        const float w11 = wy1m * wx1m;

        // corner column -> pair-element selects:
        // col0 = clamp(x0,0,383):   == xbs+1 only when x0 >= 383
        // col1 = clamp(x0+1,0,383): == xbs+1 exactly when x0 >= 0
        const bool selA = (x0 >= WW - 1);
        const bool selB = (x0 >= 0);

        const int o0 = ry0 * WW + xbs;
        const int o1 = ry1 * WW + xbs;

        float v0, v1, v2;
        {
            const v2f p0 = *(const v2f*)(xc0 + o0);
            const v2f p1 = *(const v2f*)(xc0 + o1);
            const float c00 = selA ? p0.y : p0.x;
            const float c01 = selB ? p0.y : p0.x;
            const float c10 = selA ? p1.y : p1.x;
            const float c11 = selB ? p1.y : p1.x;
            v0 = fmaf(w00, c00, fmaf(w01, c01, fmaf(w10, c10, w11 * c11)));
        }
        {
            const v2f p0 = *(const v2f*)(xc1 + o0);
            const v2f p1 = *(const v2f*)(xc1 + o1);
            const float c00 = selA ? p0.y : p0.x;
            const float c01 = selB ? p0.y : p0.x;
            const float c10 = selA ? p1.y : p1.x;
            const float c11 = selB ? p1.y : p1.x;
            v1 = fmaf(w00, c00, fmaf(w01, c01, fmaf(w10, c10, w11 * c11)));
        }
        {
            const v2f p0 = *(const v2f*)(xc2 + o0);
            const v2f p1 = *(const v2f*)(xc2 + o1);
            const float c00 = selA ? p0.y : p0.x;
            const float c01 = selB ? p0.y : p0.x;
            const float c10 = selA ? p1.y : p1.x;
            const float c11 = selB ? p1.y : p1.x;
            v2 = fmaf(w00, c00, fmaf(w01, c01, fmaf(w10, c10, w11 * c11)));
        }

        acc0 = fmaf(s_w2[0 * 27 + 0 * 9 + k], v0, acc0);
        acc0 = fmaf(s_w2[0 * 27 + 1 * 9 + k], v1, acc0);
        acc0 = fmaf(s_w2[0 * 27 + 2 * 9 + k], v2, acc0);
        acc1 = fmaf(s_w2[1 * 27 + 0 * 9 + k], v0, acc1);
        acc1 = fmaf(s_w2[1 * 27 + 1 * 9 + k], v1, acc1);
        acc1 = fmaf(s_w2[1 * 27 + 2 * 9 + k], v2, acc1);
        acc2 = fmaf(s_w2[2 * 27 + 0 * 9 + k], v0, acc2);
        acc2 = fmaf(s_w2[2 * 27 + 1 * 9 + k], v1, acc2);
        acc2 = fmaf(s_w2[2 * 27 + 2 * 9 + k], v2, acc2);
    }

    const long obase = ((long)(b * 3) * HO + ho) * WO + wo;
    __builtin_nontemporal_store(acc0, out + obase);
    __builtin_nontemporal_store(acc1, out + obase + (long)HO * WO);
    __builtin_nontemporal_store(acc2, out + obase + 2L * HO * WO);
}

extern "C" void kernel_launch(void* const* d_in, const int* in_sizes, int n_in,
                              void* d_out, int out_size, void* d_ws, size_t ws_size,
                              hipStream_t stream) {
    const float* x  = (const float*)d_in[0];
    const float* w1 = (const float*)d_in[1];
    const float* b1 = (const float*)d_in[2];
    const float* w2 = (const float*)d_in[3];
    const float* b2 = (const float*)d_in[4];
    float* out = (float*)d_out;

    const int blocks = BLOCKS_PER_BATCH * BB;   // 571*8 = 4568
    deform_fused_kernel<<<blocks, 256, 0, stream>>>(x, w1, b1, w2, b2, out);
}

// Round 6
// 132.127 us; speedup vs baseline: 1.2909x; 1.0895x over previous
//
#include <hip/hip_runtime.h>

// Fused: offset = conv3x3(x,w1)+b1 ; out = deform_conv(x, offset, w2)+b2
// x: (8,3,384,384) f32 ; out: (8,3,382,382) f32
// R6: occupancy push. Measured law across R1-R5: waves/SIMD ~= 256/VGPR
// (R2 116->19%, R4 52->38%, R3 32->73%) -- effective budget 256, not 512.
//  - channel-split offset conv: only 9 neighborhood regs live at a time
//    (peak VGPR ~40 instead of ~52). Per-oc accumulation order unchanged.
//  - __launch_bounds__(256,6): cap VGPR ~42 -> 6 waves/SIMD. (R3 lesson:
//    deficit vs natural pressure must be small; here ~0-3 regs, not 28.)
//  - transposed LDS weights (w1t[c][oc][j], w2t[k][o][c]) -> contiguous
//    use-order -> ds_read_b128 merging, ~4x fewer LDS-pipe cycles.
// Kept verified wins: XCD batch swizzle (FETCH 39->7MB), pair-gather taps
// (R5), NT stores.

#define BB 8
#define HH 384
#define WW 384
#define HO 382
#define WO 382
#define HW (HH * WW)
#define PIX_PER_BATCH (HO * WO)                              // 145924
#define BLOCKS_PER_BATCH ((PIX_PER_BATCH + 255) / 256)       // 571

typedef float v2f __attribute__((ext_vector_type(2), aligned(4)));

__global__ __launch_bounds__(256, 6) void deform_fused_kernel(
    const float* __restrict__ x,
    const float* __restrict__ w1,
    const float* __restrict__ b1,
    const float* __restrict__ w2,
    const float* __restrict__ b2,
    float* __restrict__ out)
{
    __shared__ float s_w1t[486];  // [c][oc][j] = c*162 + oc*9 + j
    __shared__ float s_b1[18];
    __shared__ float s_w2t[81];   // [k][o][c] = k*9 + o*3 + c
    __shared__ float s_b2[3];

    for (int i = threadIdx.x; i < 486; i += 256) {
        const int oc = i / 27, r = i % 27, c = r / 9, j = r % 9;
        s_w1t[c * 162 + oc * 9 + j] = w1[i];
    }
    if (threadIdx.x < 81) {
        const int i = threadIdx.x;
        const int o = i / 27, r = i % 27, c = r / 9, k = r % 9;
        s_w2t[k * 9 + o * 3 + c] = w2[i];
    }
    if (threadIdx.x < 18) s_b1[threadIdx.x] = b1[threadIdx.x];
    if (threadIdx.x < 3)  s_b2[threadIdx.x] = b2[threadIdx.x];
    __syncthreads();

    const int b    = blockIdx.x & 7;          // XCD-locality: batch per XCD
    const int tile = blockIdx.x >> 3;
    const int idx  = tile * 256 + threadIdx.x;
    if (idx >= PIX_PER_BATCH) return;

    const int wo = idx % WO;
    const int ho = idx / WO;

    const float* xb = x + (long)b * 3 * HW;

    // ---- Phase 1: 18 offset channels, channel-split (9 x-regs live max) ----
    float off[18];
#pragma unroll
    for (int oc = 0; oc < 18; ++oc) off[oc] = s_b1[oc];

#pragma unroll
    for (int c = 0; c < 3; ++c) {
        float xr[9];
#pragma unroll
        for (int i = 0; i < 3; ++i) {
            const float* rp = xb + c * HW + (ho + i) * WW + wo;
            const v2f p = *(const v2f*)rp;
            xr[i * 3 + 0] = p.x;
            xr[i * 3 + 1] = p.y;
            xr[i * 3 + 2] = rp[2];
        }
        const float* wc = s_w1t + c * 162;
#pragma unroll
        for (int oc = 0; oc < 18; ++oc)
#pragma unroll
            for (int j = 0; j < 9; ++j)
                off[oc] = fmaf(xr[j], wc[oc * 9 + j], off[oc]);
    }

    // ---- Phase 2: 9 bilinear taps (pair-gather) ----
    float acc0 = s_b2[0], acc1 = s_b2[1], acc2 = s_b2[2];

    const float* xc0 = xb;
    const float* xc1 = xb + HW;
    const float* xc2 = xb + 2 * HW;

#pragma unroll
    for (int k = 0; k < 9; ++k) {
        const int kh = k / 3, kw = k % 3;
        const float py = (float)(ho + kh) + off[2 * k];
        const float px = (float)(wo + kw) + off[2 * k + 1];
        const float y0f = floorf(py);
        const float x0f = floorf(px);
        const float wy = py - y0f;
        const float wx = px - x0f;
        const int y0 = (int)y0f;
        const int x0 = (int)x0f;

        const int ry0 = min(max(y0, 0), HH - 1);
        const int ry1 = min(max(y0 + 1, 0), HH - 1);
        const int xbs = min(max(x0, 0), WW - 2);

        // validity folded into weights (matches ref: wgt * valid)
        const bool vy0 = (y0 >= 0) & (y0 <= HH - 1);
        const bool vy1 = (y0 >= -1) & (y0 <= HH - 2);
        const bool vx0 = (x0 >= 0) & (x0 <= WW - 1);
        const bool vx1 = (x0 >= -1) & (x0 <= WW - 2);
        const float wy0m = vy0 ? (1.f - wy) : 0.f;
        const float wy1m = vy1 ? wy : 0.f;
        const float wx0m = vx0 ? (1.f - wx) : 0.f;
        const float wx1m = vx1 ? wx : 0.f;
        const float w00 = wy0m * wx0m;
        const float w01 = wy0m * wx1m;
        const float w10 = wy1m * wx0m;
        const float w11 = wy1m * wx1m;

        // corner column -> pair-element selects
        const bool selA = (x0 >= WW - 1);   // col0 == xbs+1 only when x0>=383
        const bool selB = (x0 >= 0);        // col1 == xbs+1 exactly when x0>=0

        const int o0 = ry0 * WW + xbs;
        const int o1 = ry1 * WW + xbs;

        float v0, v1, v2;
        {
            const v2f p0 = *(const v2f*)(xc0 + o0);
            const v2f p1 = *(const v2f*)(xc0 + o1);
            const float c00 = selA ? p0.y : p0.x;
            const float c01 = selB ? p0.y : p0.x;
            const float c10 = selA ? p1.y : p1.x;
            const float c11 = selB ? p1.y : p1.x;
            v0 = fmaf(w00, c00, fmaf(w01, c01, fmaf(w10, c10, w11 * c11)));
        }
        {
            const v2f p0 = *(const v2f*)(xc1 + o0);
            const v2f p1 = *(const v2f*)(xc1 + o1);
            const float c00 = selA ? p0.y : p0.x;
            const float c01 = selB ? p0.y : p0.x;
            const float c10 = selA ? p1.y : p1.x;
            const float c11 = selB ? p1.y : p1.x;
            v1 = fmaf(w00, c00, fmaf(w01, c01, fmaf(w10, c10, w11 * c11)));
        }
        {
            const v2f p0 = *(const v2f*)(xc2 + o0);
            const v2f p1 = *(const v2f*)(xc2 + o1);
            const float c00 = selA ? p0.y : p0.x;
            const float c01 = selB ? p0.y : p0.x;
            const float c10 = selA ? p1.y : p1.x;
            const float c11 = selB ? p1.y : p1.x;
            v2 = fmaf(w00, c00, fmaf(w01, c01, fmaf(w10, c10, w11 * c11)));
        }

        const float* wk = s_w2t + k * 9;   // [o][c] contiguous
        acc0 = fmaf(wk[0], v0, acc0);
        acc0 = fmaf(wk[1], v1, acc0);
        acc0 = fmaf(wk[2], v2, acc0);
        acc1 = fmaf(wk[3], v0, acc1);
        acc1 = fmaf(wk[4], v1, acc1);
        acc1 = fmaf(wk[5], v2, acc1);
        acc2 = fmaf(wk[6], v0, acc2);
        acc2 = fmaf(wk[7], v1, acc2);
        acc2 = fmaf(wk[8], v2, acc2);
    }

    const long obase = ((long)(b * 3) * HO + ho) * WO + wo;
    __builtin_nontemporal_store(acc0, out + obase);
    __builtin_nontemporal_store(acc1, out + obase + (long)HO * WO);
    __builtin_nontemporal_store(acc2, out + obase + 2L * HO * WO);
}

extern "C" void kernel_launch(void* const* d_in, const int* in_sizes, int n_in,
                              void* d_out, int out_size, void* d_ws, size_t ws_size,
                              hipStream_t stream) {
    const float* x  = (const float*)d_in[0];
    const float* w1 = (const float*)d_in[1];
    const float* b1 = (const float*)d_in[2];
    const float* w2 = (const float*)d_in[3];
    const float* b2 = (const float*)d_in[4];
    float* out = (float*)d_out;

    const int blocks = BLOCKS_PER_BATCH * BB;   // 571*8 = 4568
    deform_fused_kernel<<<blocks, 256, 0, stream>>>(x, w1, b1, w2, b2, out);
}

// Round 7
// 130.338 us; speedup vs baseline: 1.3086x; 1.0137x over previous
//
#include <hip/hip_runtime.h>

// Fused: offset = conv3x3(x,w1)+b1 ; out = deform_conv(x, offset, w2)+b2
// x: (8,3,384,384) f32 ; out: (8,3,382,382) f32
// R7: packed-fp32 push (v_pk_fma_f32 = CDNA4 full-rate packed FMA; scalar
// v_fma_f32 is half-rate).
//  - phase 1: (dy,dx) pairs as v2f accumulators, w1 staged as v2f pairs
//    s_w1p[c][j][k] -> 486 scalar FMA -> 243 pk_fma. Per-oc order unchanged.
//  - phase 2: selects folded into weights: e0/e1 = weights on (p.x,p.y);
//    v_c = f0v.p0 + f1v.p1. Kills 12 cndmask/tap, corner FMAs 12 -> 6pk+3add.
//  - epilogue: acc0/acc1 packed via paired w2 layout -> 9 -> 6 issues/tap.
// Kept verified: XCD batch swizzle (FETCH 39->7MB), channel-split phase 1
// (VGPR 52->36, occ 62%), launch_bounds(256,6), NT stores.
// R3 lesson: never cap VGPR below natural pressure by >~4.

#define BB 8
#define HH 384
#define WW 384
#define HO 382
#define WO 382
#define HW (HH * WW)
#define PIX_PER_BATCH (HO * WO)                              // 145924
#define BLOCKS_PER_BATCH ((PIX_PER_BATCH + 255) / 256)       // 571

typedef float v2f __attribute__((ext_vector_type(2), aligned(4)));

static __device__ __forceinline__ v2f fma2(v2f a, v2f b, v2f c) {
    return __builtin_elementwise_fma(a, b, c);
}

__global__ __launch_bounds__(256, 6) void deform_fused_kernel(
    const float* __restrict__ x,
    const float* __restrict__ w1,
    const float* __restrict__ b1,
    const float* __restrict__ w2,
    const float* __restrict__ b2,
    float* __restrict__ out)
{
    // w1 pairs: s_w1p[((c*9+j)*9+k)] = (w1[oc=2k][c][j], w1[oc=2k+1][c][j])
    __shared__ float s_w1p[486];
    __shared__ float s_b1[18];
    // w2: pairs (o=0,1) s_w2p[(k*3+c)] ; scalar o=2 s_w2s[k*3+c]
    __shared__ float s_w2p[54];
    __shared__ float s_w2s[27];
    __shared__ float s_b2[3];

    for (int i = threadIdx.x; i < 486; i += 256) {
        const int oc = i / 27, rem = i % 27, c = rem / 9, j = rem % 9;
        const int k = oc >> 1, comp = oc & 1;
        s_w1p[((c * 9 + j) * 9 + k) * 2 + comp] = w1[i];
    }
    if (threadIdx.x < 81) {
        const int i = threadIdx.x;
        const int o = i / 27, c = (i % 27) / 9, k = i % 9;
        if (o < 2) s_w2p[(k * 3 + c) * 2 + o] = w2[i];
        else       s_w2s[k * 3 + c] = w2[i];
    }
    if (threadIdx.x < 18) s_b1[threadIdx.x] = b1[threadIdx.x];
    if (threadIdx.x < 3)  s_b2[threadIdx.x] = b2[threadIdx.x];
    __syncthreads();

    const int b    = blockIdx.x & 7;          // XCD-locality: batch per XCD
    const int tile = blockIdx.x >> 3;
    const int idx  = tile * 256 + threadIdx.x;
    if (idx >= PIX_PER_BATCH) return;

    const int wo = idx % WO;
    const int ho = idx / WO;

    const float* xb = x + (long)b * 3 * HW;

    // ---- Phase 1: 9 (dy,dx) pairs, channel-split, packed FMA ----
    v2f off2[9];
#pragma unroll
    for (int k = 0; k < 9; ++k) {
        v2f v; v.x = s_b1[2 * k]; v.y = s_b1[2 * k + 1];
        off2[k] = v;
    }

    const v2f* w1p = (const v2f*)s_w1p;
#pragma unroll
    for (int c = 0; c < 3; ++c) {
        float xr[9];
#pragma unroll
        for (int i = 0; i < 3; ++i) {
            const float* rp = xb + c * HW + (ho + i) * WW + wo;
            const v2f p = *(const v2f*)rp;
            xr[i * 3 + 0] = p.x;
            xr[i * 3 + 1] = p.y;
            xr[i * 3 + 2] = rp[2];
        }
#pragma unroll
        for (int j = 0; j < 9; ++j) {
            v2f xj; xj.x = xr[j]; xj.y = xr[j];
            const v2f* wrow = w1p + (c * 9 + j) * 9;
#pragma unroll
            for (int k = 0; k < 9; ++k)
                off2[k] = fma2(xj, wrow[k], off2[k]);
        }
    }

    // ---- Phase 2: 9 bilinear taps ----
    float acc0 = s_b2[0], acc1 = s_b2[1], acc2 = s_b2[2];

    const float* xc0 = xb;
    const float* xc1 = xb + HW;
    const float* xc2 = xb + 2 * HW;
    const v2f* w2p = (const v2f*)s_w2p;

#pragma unroll
    for (int k = 0; k < 9; ++k) {
        const int kh = k / 3, kw = k % 3;
        v2f pos; pos.x = (float)(ho + kh); pos.y = (float)(wo + kw);
        pos += off2[k];
        const v2f fl = __builtin_elementwise_floor(pos);
        const v2f fr = pos - fl;               // (wy, wx)
        const int y0 = (int)fl.x;
        const int x0 = (int)fl.y;

        const int ry0 = min(max(y0, 0), HH - 1);
        const int ry1 = min(max(y0 + 1, 0), HH - 1);
        const int xbs = min(max(x0, 0), WW - 2);

        // validity folded into weights (matches ref: wgt * valid)
        const bool vy0 = (y0 >= 0) & (y0 <= HH - 1);
        const bool vy1 = (y0 >= -1) & (y0 <= HH - 2);
        const bool vx0 = (x0 >= 0) & (x0 <= WW - 1);
        const bool vx1 = (x0 >= -1) & (x0 <= WW - 2);
        const float wy0m = vy0 ? (1.f - fr.x) : 0.f;
        const float wy1m = vy1 ? fr.x : 0.f;
        const float wx0m = vx0 ? (1.f - fr.y) : 0.f;
        const float wx1m = vx1 ? fr.y : 0.f;

        // fold corner-column selects into (p.x, p.y) weights:
        // col0 = p.y only when x0>=383 (selA); col1 = p.y exactly when x0>=0 (selB)
        const bool selA = (x0 >= WW - 1);
        const bool selB = (x0 >= 0);
        const float e0 = (selA ? 0.f : wx0m) + (selB ? 0.f : wx1m); // weight on p.x
        const float e1 = (selA ? wx0m : 0.f) + (selB ? wx1m : 0.f); // weight on p.y
        v2f f0; f0.x = wy0m * e0; f0.y = wy0m * e1;   // row y0: (p0.x, p0.y)
        v2f f1; f1.x = wy1m * e0; f1.y = wy1m * e1;   // row y1: (p1.x, p1.y)

        const int o0 = ry0 * WW + xbs;
        const int o1 = ry1 * WW + xbs;

        const v2f a0 = *(const v2f*)(xc0 + o0);
        const v2f a1 = *(const v2f*)(xc0 + o1);
        const v2f b0 = *(const v2f*)(xc1 + o0);
        const v2f b1v = *(const v2f*)(xc1 + o1);
        const v2f c0 = *(const v2f*)(xc2 + o0);
        const v2f c1 = *(const v2f*)(xc2 + o1);

        const v2f t0 = fma2(f1, a1, f0 * a0);
        const v2f t1 = fma2(f1, b1v, f0 * b0);
        const v2f t2 = fma2(f1, c1, f0 * c0);
        const float v0 = t0.x + t0.y;
        const float v1 = t1.x + t1.y;
        const float v2v = t2.x + t2.y;

        // epilogue: packed (acc0,acc1), scalar acc2
        v2f acc01; acc01.x = acc0; acc01.y = acc1;
        v2f vv;
        vv.x = v0; vv.y = v0; acc01 = fma2(vv, w2p[k * 3 + 0], acc01);
        vv.x = v1; vv.y = v1; acc01 = fma2(vv, w2p[k * 3 + 1], acc01);
        vv.x = v2v; vv.y = v2v; acc01 = fma2(vv, w2p[k * 3 + 2], acc01);
        acc0 = acc01.x; acc1 = acc01.y;
        acc2 = fmaf(s_w2s[k * 3 + 0], v0, acc2);
        acc2 = fmaf(s_w2s[k * 3 + 1], v1, acc2);
        acc2 = fmaf(s_w2s[k * 3 + 2], v2v, acc2);
    }

    const long obase = ((long)(b * 3) * HO + ho) * WO + wo;
    __builtin_nontemporal_store(acc0, out + obase);
    __builtin_nontemporal_store(acc1, out + obase + (long)HO * WO);
    __builtin_nontemporal_store(acc2, out + obase + 2L * HO * WO);
}

extern "C" void kernel_launch(void* const* d_in, const int* in_sizes, int n_in,
                              void* d_out, int out_size, void* d_ws, size_t ws_size,
                              hipStream_t stream) {
    const float* x  = (const float*)d_in[0];
    const float* w1 = (const float*)d_in[1];
    const float* b1 = (const float*)d_in[2];
    const float* w2 = (const float*)d_in[3];
    const float* b2 = (const float*)d_in[4];
    float* out = (float*)d_out;

    const int blocks = BLOCKS_PER_BATCH * BB;   // 571*8 = 4568
    deform_fused_kernel<<<blocks, 256, 0, stream>>>(x, w1, b1, w2, b2, out);
}

// Round 8
// 120.985 us; speedup vs baseline: 1.4098x; 1.0773x over previous
//
#include <hip/hip_runtime.h>

// Fused: offset = conv3x3(x,w1)+b1 ; out = deform_conv(x, offset, w2)+b2
// x: (8,3,384,384) f32 ; out: (8,3,382,382) f32
// R8: NHWC4 layout push. R7 showed VALUBusy 51->37% with dur flat => gather
// latency / MLP bound, not VALU. NCHW gathers: 54x8B loads/thread, 3 channels
// 590KB apart (~6 cachelines/tap). Fix: pre-transpose x -> (8,384,384,4) f32
// in d_ws (pad ch 4). Then each bilinear corner = ONE aligned 16B load with
// all 3 channels; both corners of a row are 32B contiguous.
//   - phase 2: 36 dwordx4 loads (was 54 dword2), ~2 cachelines/tap (was ~6)
//   - phase 1: 9 float4 pixel loads, only 4 neighborhood regs live
//   - transpose kernel uses the same XCD swizzle -> producer/consumer L2 hit
// Kept verified: XCD batch swizzle, e0/e1 select-folding (R7), pk_fma pairs,
// NT stores. launch_bounds(256,5): cap ~51 vs natural ~45-48 (R3 lesson).
// Fallback to R7 kernel if ws_size < 19MB.

#define BB 8
#define HH 384
#define WW 384
#define HO 382
#define WO 382
#define HW (HH * WW)
#define PIX_PER_BATCH (HO * WO)                              // 145924
#define BLOCKS_PER_BATCH ((PIX_PER_BATCH + 255) / 256)       // 571
#define TR_BLOCKS_PER_BATCH (HW / 256)                       // 576 (exact)

typedef float v2f __attribute__((ext_vector_type(2), aligned(4)));
typedef float v4f __attribute__((ext_vector_type(4), aligned(16)));

static __device__ __forceinline__ v2f fma2(v2f a, v2f b, v2f c) {
    return __builtin_elementwise_fma(a, b, c);
}
static __device__ __forceinline__ v4f fma4(v4f a, v4f b, v4f c) {
    return __builtin_elementwise_fma(a, b, c);
}

// ---------------- transpose: NCHW -> NHWC4 (into d_ws) ----------------
__global__ __launch_bounds__(256) void nchw_to_nhwc4(
    const float* __restrict__ x, v4f* __restrict__ xt)
{
    const int b    = blockIdx.x & 7;          // same XCD mapping as consumer
    const int tile = blockIdx.x >> 3;
    const int idx  = tile * 256 + threadIdx.x;   // 576*256 == HW exactly
    const float* xb = x + (long)b * 3 * HW;
    v4f v;
    v.x = xb[idx];
    v.y = xb[HW + idx];
    v.z = xb[2 * HW + idx];
    v.w = 0.f;
    xt[(long)b * HW + idx] = v;
}

// ---------------- main fused kernel (NHWC4 input) ----------------
__global__ __launch_bounds__(256, 5) void deform_fused_nhwc(
    const v4f* __restrict__ xt,
    const float* __restrict__ w1,
    const float* __restrict__ b1,
    const float* __restrict__ w2,
    const float* __restrict__ b2,
    float* __restrict__ out)
{
    // w1 pairs: s_w1p[((j*3+c)*9+k)*2+comp] = w1[oc=2k+comp][c][j]
    __shared__ float s_w1p[486];
    __shared__ float s_b1[18];
    // w2: pairs (o=0,1) + scalar o=2
    __shared__ float s_w2p[54];
    __shared__ float s_w2s[27];
    __shared__ float s_b2[3];

    for (int i = threadIdx.x; i < 486; i += 256) {
        const int oc = i / 27, rem = i % 27, c = rem / 9, j = rem % 9;
        const int k = oc >> 1, comp = oc & 1;
        s_w1p[((j * 3 + c) * 9 + k) * 2 + comp] = w1[i];
    }
    if (threadIdx.x < 81) {
        const int i = threadIdx.x;
        const int o = i / 27, c = (i % 27) / 9, k = i % 9;
        if (o < 2) s_w2p[(k * 3 + c) * 2 + o] = w2[i];
        else       s_w2s[k * 3 + c] = w2[i];
    }
    if (threadIdx.x < 18) s_b1[threadIdx.x] = b1[threadIdx.x];
    if (threadIdx.x < 3)  s_b2[threadIdx.x] = b2[threadIdx.x];
    __syncthreads();

    const int b    = blockIdx.x & 7;          // XCD-locality: batch per XCD
    const int tile = blockIdx.x >> 3;
    const int idx  = tile * 256 + threadIdx.x;
    if (idx >= PIX_PER_BATCH) return;

    const int wo = idx % WO;
    const int ho = idx / WO;

    const v4f* xtb = xt + (long)b * HW;

    // ---- Phase 1: 9 (dy,dx) pairs, pixel-major, packed FMA ----
    v2f off2[9];
#pragma unroll
    for (int k = 0; k < 9; ++k) {
        v2f v; v.x = s_b1[2 * k]; v.y = s_b1[2 * k + 1];
        off2[k] = v;
    }

    const v2f* w1p = (const v2f*)s_w1p;
#pragma unroll
    for (int j = 0; j < 9; ++j) {
        const int i = j / 3, jj = j % 3;
        const v4f q = xtb[(ho + i) * WW + (wo + jj)];
#pragma unroll
        for (int c = 0; c < 3; ++c) {
            const float xc = (c == 0) ? q.x : (c == 1) ? q.y : q.z;
            v2f xcv; xcv.x = xc; xcv.y = xc;
            const v2f* wrow = w1p + (j * 3 + c) * 9;
#pragma unroll
            for (int k = 0; k < 9; ++k)
                off2[k] = fma2(xcv, wrow[k], off2[k]);
        }
    }

    // ---- Phase 2: 9 bilinear taps, one float4 per corner ----
    float acc0 = s_b2[0], acc1 = s_b2[1], acc2 = s_b2[2];
    const v2f* w2p = (const v2f*)s_w2p;

#pragma unroll
    for (int k = 0; k < 9; ++k) {
        const int kh = k / 3, kw = k % 3;
        v2f pos; pos.x = (float)(ho + kh); pos.y = (float)(wo + kw);
        pos += off2[k];
        const v2f fl = __builtin_elementwise_floor(pos);
        const v2f fr = pos - fl;               // (wy, wx)
        const int y0 = (int)fl.x;
        const int x0 = (int)fl.y;

        const int ry0 = min(max(y0, 0), HH - 1);
        const int ry1 = min(max(y0 + 1, 0), HH - 1);
        const int xbs = min(max(x0, 0), WW - 2);

        // validity folded into weights (matches ref: wgt * valid)
        const bool vy0 = (y0 >= 0) & (y0 <= HH - 1);
        const bool vy1 = (y0 >= -1) & (y0 <= HH - 2);
        const bool vx0 = (x0 >= 0) & (x0 <= WW - 1);
        const bool vx1 = (x0 >= -1) & (x0 <= WW - 2);
        const float wy0m = vy0 ? (1.f - fr.x) : 0.f;
        const float wy1m = vy1 ? fr.x : 0.f;
        const float wx0m = vx0 ? (1.f - fr.y) : 0.f;
        const float wx1m = vx1 ? fr.y : 0.f;

        // fold corner-column selects into (col xbs, col xbs+1) weights (R7)
        const bool selA = (x0 >= WW - 1);
        const bool selB = (x0 >= 0);
        const float e0 = (selA ? 0.f : wx0m) + (selB ? 0.f : wx1m);
        const float e1 = (selA ? wx0m : 0.f) + (selB ? wx1m : 0.f);
        const float g00 = wy0m * e0, g01 = wy0m * e1;
        const float g10 = wy1m * e0, g11 = wy1m * e1;

        const int o0 = ry0 * WW + xbs;
        const int o1 = ry1 * WW + xbs;

        const v4f q00 = xtb[o0];
        const v4f q01 = xtb[o0 + 1];
        const v4f q10 = xtb[o1];
        const v4f q11 = xtb[o1 + 1];

        v4f gv; gv.x = g00; gv.y = g00; gv.z = g00; gv.w = g00;
        v4f t4 = gv * q00;
        gv.x = g01; gv.y = g01; gv.z = g01; gv.w = g01;
        t4 = fma4(gv, q01, t4);
        gv.x = g10; gv.y = g10; gv.z = g10; gv.w = g10;
        t4 = fma4(gv, q10, t4);
        gv.x = g11; gv.y = g11; gv.z = g11; gv.w = g11;
        t4 = fma4(gv, q11, t4);

        const float v0 = t4.x, v1 = t4.y, v2v = t4.z;

        // epilogue: packed (acc0,acc1), scalar acc2
        v2f acc01; acc01.x = acc0; acc01.y = acc1;
        v2f vv;
        vv.x = v0;  vv.y = v0;  acc01 = fma2(vv, w2p[k * 3 + 0], acc01);
        vv.x = v1;  vv.y = v1;  acc01 = fma2(vv, w2p[k * 3 + 1], acc01);
        vv.x = v2v; vv.y = v2v; acc01 = fma2(vv, w2p[k * 3 + 2], acc01);
        acc0 = acc01.x; acc1 = acc01.y;
        acc2 = fmaf(s_w2s[k * 3 + 0], v0, acc2);
        acc2 = fmaf(s_w2s[k * 3 + 1], v1, acc2);
        acc2 = fmaf(s_w2s[k * 3 + 2], v2v, acc2);
    }

    const long obase = ((long)(b * 3) * HO + ho) * WO + wo;
    __builtin_nontemporal_store(acc0, out + obase);
    __builtin_nontemporal_store(acc1, out + obase + (long)HO * WO);
    __builtin_nontemporal_store(acc2, out + obase + 2L * HO * WO);
}

// ---------------- fallback (R7 kernel, NCHW) if ws too small ----------------
__global__ __launch_bounds__(256, 6) void deform_fused_fallback(
    const float* __restrict__ x,
    const float* __restrict__ w1,
    const float* __restrict__ b1,
    const float* __restrict__ w2,
    const float* __restrict__ b2,
    float* __restrict__ out)
{
    __shared__ float s_w1p[486];
    __shared__ float s_b1[18];
    __shared__ float s_w2p[54];
    __shared__ float s_w2s[27];
    __shared__ float s_b2[3];

    for (int i = threadIdx.x; i < 486; i += 256) {
        const int oc = i / 27, rem = i % 27, c = rem / 9, j = rem % 9;
        const int k = oc >> 1, comp = oc & 1;
        s_w1p[((c * 9 + j) * 9 + k) * 2 + comp] = w1[i];
    }
    if (threadIdx.x < 81) {
        const int i = threadIdx.x;
        const int o = i / 27, c = (i % 27) / 9, k = i % 9;
        if (o < 2) s_w2p[(k * 3 + c) * 2 + o] = w2[i];
        else       s_w2s[k * 3 + c] = w2[i];
    }
    if (threadIdx.x < 18) s_b1[threadIdx.x] = b1[threadIdx.x];
    if (threadIdx.x < 3)  s_b2[threadIdx.x] = b2[threadIdx.x];
    __syncthreads();

    const int b    = blockIdx.x & 7;
    const int tile = blockIdx.x >> 3;
    const int idx  = tile * 256 + threadIdx.x;
    if (idx >= PIX_PER_BATCH) return;

    const int wo = idx % WO;
    const int ho = idx / WO;

    const float* xb = x + (long)b * 3 * HW;

    v2f off2[9];
#pragma unroll
    for (int k = 0; k < 9; ++k) {
        v2f v; v.x = s_b1[2 * k]; v.y = s_b1[2 * k + 1];
        off2[k] = v;
    }

    const v2f* w1p = (const v2f*)s_w1p;
#pragma unroll
    for (int c = 0; c < 3; ++c) {
        float xr[9];
#pragma unroll
        for (int i = 0; i < 3; ++i) {
            const float* rp = xb + c * HW + (ho + i) * WW + wo;
            const v2f p = *(const v2f*)rp;
            xr[i * 3 + 0] = p.x;
            xr[i * 3 + 1] = p.y;
            xr[i * 3 + 2] = rp[2];
        }
#pragma unroll
        for (int j = 0; j < 9; ++j) {
            v2f xj; xj.x = xr[j]; xj.y = xr[j];
            const v2f* wrow = w1p + (c * 9 + j) * 9;
#pragma unroll
            for (int k = 0; k < 9; ++k)
                off2[k] = fma2(xj, wrow[k], off2[k]);
        }
    }

    float acc0 = s_b2[0], acc1 = s_b2[1], acc2 = s_b2[2];
    const float* xc0 = xb;
    const float* xc1 = xb + HW;
    const float* xc2 = xb + 2 * HW;
    const v2f* w2p = (const v2f*)s_w2p;

#pragma unroll
    for (int k = 0; k < 9; ++k) {
        const int kh = k / 3, kw = k % 3;
        v2f pos; pos.x = (float)(ho + kh); pos.y = (float)(wo + kw);
        pos += off2[k];
        const v2f fl = __builtin_elementwise_floor(pos);
        const v2f fr = pos - fl;
        const int y0 = (int)fl.x;
        const int x0 = (int)fl.y;

        const int ry0 = min(max(y0, 0), HH - 1);
        const int ry1 = min(max(y0 + 1, 0), HH - 1);
        const int xbs = min(max(x0, 0), WW - 2);

        const bool vy0 = (y0 >= 0) & (y0 <= HH - 1);
        const bool vy1 = (y0 >= -1) & (y0 <= HH - 2);
        const bool vx0 = (x0 >= 0) & (x0 <= WW - 1);
        const bool vx1 = (x0 >= -1) & (x0 <= WW - 2);
        const float wy0m = vy0 ? (1.f - fr.x) : 0.f;
        const float wy1m = vy1 ? fr.x : 0.f;
        const float wx0m = vx0 ? (1.f - fr.y) : 0.f;
        const float wx1m = vx1 ? fr.y : 0.f;

        const bool selA = (x0 >= WW - 1);
        const bool selB = (x0 >= 0);
        const float e0 = (selA ? 0.f : wx0m) + (selB ? 0.f : wx1m);
        const float e1 = (selA ? wx0m : 0.f) + (selB ? wx1m : 0.f);
        v2f f0; f0.x = wy0m * e0; f0.y = wy0m * e1;
        v2f f1; f1.x = wy1m * e0; f1.y = wy1m * e1;

        const int o0 = ry0 * WW + xbs;
        const int o1 = ry1 * WW + xbs;

        const v2f a0 = *(const v2f*)(xc0 + o0);
        const v2f a1 = *(const v2f*)(xc0 + o1);
        const v2f b0 = *(const v2f*)(xc1 + o0);
        const v2f b1v = *(const v2f*)(xc1 + o1);
        const v2f c0 = *(const v2f*)(xc2 + o0);
        const v2f c1 = *(const v2f*)(xc2 + o1);

        const v2f t0 = fma2(f1, a1, f0 * a0);
        const v2f t1 = fma2(f1, b1v, f0 * b0);
        const v2f t2 = fma2(f1, c1, f0 * c0);
        const float v0 = t0.x + t0.y;
        const float v1 = t1.x + t1.y;
        const float v2v = t2.x + t2.y;

        v2f acc01; acc01.x = acc0; acc01.y = acc1;
        v2f vv;
        vv.x = v0;  vv.y = v0;  acc01 = fma2(vv, w2p[k * 3 + 0], acc01);
        vv.x = v1;  vv.y = v1;  acc01 = fma2(vv, w2p[k * 3 + 1], acc01);
        vv.x = v2v; vv.y = v2v; acc01 = fma2(vv, w2p[k * 3 + 2], acc01);
        acc0 = acc01.x; acc1 = acc01.y;
        acc2 = fmaf(s_w2s[k * 3 + 0], v0, acc2);
        acc2 = fmaf(s_w2s[k * 3 + 1], v1, acc2);
        acc2 = fmaf(s_w2s[k * 3 + 2], v2v, acc2);
    }

    const long obase = ((long)(b * 3) * HO + ho) * WO + wo;
    __builtin_nontemporal_store(acc0, out + obase);
    __builtin_nontemporal_store(acc1, out + obase + (long)HO * WO);
    __builtin_nontemporal_store(acc2, out + obase + 2L * HO * WO);
}

extern "C" void kernel_launch(void* const* d_in, const int* in_sizes, int n_in,
                              void* d_out, int out_size, void* d_ws, size_t ws_size,
                              hipStream_t stream) {
    const float* x  = (const float*)d_in[0];
    const float* w1 = (const float*)d_in[1];
    const float* b1 = (const float*)d_in[2];
    const float* w2 = (const float*)d_in[3];
    const float* b2 = (const float*)d_in[4];
    float* out = (float*)d_out;

    const size_t need = (size_t)BB * HW * 4 * sizeof(float);   // 18.9 MB
    if (ws_size >= need) {
        nchw_to_nhwc4<<<TR_BLOCKS_PER_BATCH * BB, 256, 0, stream>>>(x, (v4f*)d_ws);
        deform_fused_nhwc<<<BLOCKS_PER_BATCH * BB, 256, 0, stream>>>(
            (const v4f*)d_ws, w1, b1, w2, b2, out);
    } else {
        deform_fused_fallback<<<BLOCKS_PER_BATCH * BB, 256, 0, stream>>>(
            x, w1, b1, w2, b2, out);
    }
}